// Round 4
// baseline (1400.579 us; speedup 1.0000x reference)
//
#include <hip/hip_runtime.h>
#include <cstdint>
#include <cstddef>

typedef __bf16 bf16;
typedef __bf16 bf16x4 __attribute__((ext_vector_type(4)));
typedef __bf16 bf16x8 __attribute__((ext_vector_type(8)));
typedef float f32x4 __attribute__((ext_vector_type(4)));

static_assert(sizeof(bf16x8) == 16, "bf16x8 must be 16B");

#define NTOK 100352   // 32 * 3136
#define CDIM 384

// ---------------- fp32 -> bf16 weight conversion ----------------
__global__ __launch_bounds__(256) void cvt_k(const float* __restrict__ in,
                                             bf16* __restrict__ out, int n)
{
    const int i = (blockIdx.x * 256 + threadIdx.x) * 4;
    if (i < n) {
        const float4 v = *(const float4*)(in + i);
        bf16x4 o;
        o[0] = (bf16)v.x; o[1] = (bf16)v.y; o[2] = (bf16)v.z; o[3] = (bf16)v.w;
        *(bf16x4*)(out + i) = o;
    }
}

// ---------------- LayerNorm, fp32 input -> bf16 output (row per wave) ----------------
__global__ __launch_bounds__(256) void ln32_k(const float* __restrict__ x,
    const float* __restrict__ g, const float* __restrict__ b, bf16* __restrict__ y)
{
    const int wave = threadIdx.x >> 6, lane = threadIdx.x & 63;
    const size_t row = (size_t)blockIdx.x * 4 + wave;
    const float2* xr = (const float2*)(x + row * CDIM);
    float v[6];
    float s = 0.f, s2 = 0.f;
#pragma unroll
    for (int i = 0; i < 3; i++) {
        const float2 t = xr[lane + i * 64];
        v[2 * i] = t.x; v[2 * i + 1] = t.y;
        s += t.x + t.y; s2 += t.x * t.x + t.y * t.y;
    }
#pragma unroll
    for (int off = 32; off > 0; off >>= 1) {
        s  += __shfl_xor(s, off);
        s2 += __shfl_xor(s2, off);
    }
    const float mu   = s * (1.f / CDIM);
    const float rstd = rsqrtf(s2 * (1.f / CDIM) - mu * mu + 1e-5f);
    const float2* gu = (const float2*)g;
    const float2* bu = (const float2*)b;
    uint32_t* yu = (uint32_t*)(y + row * CDIM);
#pragma unroll
    for (int i = 0; i < 3; i++) {
        const float2 gg = gu[lane + i * 64], bb = bu[lane + i * 64];
        const float o0 = (v[2 * i] - mu) * rstd * gg.x + bb.x;
        const float o1 = (v[2 * i + 1] - mu) * rstd * gg.y + bb.y;
        const uint32_t pk = (uint32_t)__builtin_bit_cast(unsigned short, (bf16)o0)
                          | ((uint32_t)__builtin_bit_cast(unsigned short, (bf16)o1) << 16);
        yu[lane + i * 64] = pk;
    }
}

// ---------------- GEMM: C = A(MxK) @ B(NxK)^T + bias [+ gelu | + res] ----------------
// 128x128 tile, BK=32, 4 waves (2x2), each wave 64x64 via 4x4 of 16x16x32 bf16 MFMA.
// EPI: 0 = +bias, 1 = +bias then exact GELU, 2 = +bias +res(fp32)
// TO:  output element type (bf16 when feeding another MFMA consumer, float for
//      the fp32 residual stream / final output).
template <int EPI, typename TO>
__global__ __launch_bounds__(256) void gemm_bt(
    const bf16* __restrict__ A, const bf16* __restrict__ Bm,
    const float* __restrict__ bias, const float* __restrict__ res,
    TO* __restrict__ Cc, int N, int K)
{
    __shared__ __align__(16) bf16 aT[128 * 32];
    __shared__ __align__(16) bf16 bT[128 * 32];
    const int tid = threadIdx.x;
    const int m0 = blockIdx.y * 128, n0 = blockIdx.x * 128;
    const int wave = tid >> 6, lane = tid & 63;
    const int wm = (wave >> 1) * 64, wn = (wave & 1) * 64;
    const int lm = lane & 15, lk = (lane >> 4) * 8;
    const int r0 = tid >> 2, cc0 = (tid & 3) * 8;

    f32x4 acc[4][4] = {};

    const bf16* Ap0 = A + (size_t)(m0 + r0) * K + cc0;
    const bf16* Ap1 = A + (size_t)(m0 + r0 + 64) * K + cc0;
    const bf16* Bp0 = Bm + (size_t)(n0 + r0) * K + cc0;
    const bf16* Bp1 = Bm + (size_t)(n0 + r0 + 64) * K + cc0;

    for (int k0 = 0; k0 < K; k0 += 32) {
        const bf16x8 av0 = *(const bf16x8*)(Ap0 + k0);
        const bf16x8 av1 = *(const bf16x8*)(Ap1 + k0);
        const bf16x8 bv0 = *(const bf16x8*)(Bp0 + k0);
        const bf16x8 bv1 = *(const bf16x8*)(Bp1 + k0);
        __syncthreads();  // previous iteration's ds_reads done before overwrite
        *(bf16x8*)&aT[r0 * 32 + cc0]        = av0;
        *(bf16x8*)&aT[(r0 + 64) * 32 + cc0] = av1;
        *(bf16x8*)&bT[r0 * 32 + cc0]        = bv0;
        *(bf16x8*)&bT[(r0 + 64) * 32 + cc0] = bv1;
        __syncthreads();
        bf16x8 af[4], bfr[4];
#pragma unroll
        for (int i = 0; i < 4; i++)
            af[i] = *(const bf16x8*)&aT[(wm + i * 16 + lm) * 32 + lk];
#pragma unroll
        for (int i = 0; i < 4; i++)
            bfr[i] = *(const bf16x8*)&bT[(wn + i * 16 + lm) * 32 + lk];
#pragma unroll
        for (int mi = 0; mi < 4; mi++)
#pragma unroll
            for (int ni = 0; ni < 4; ni++)
                acc[mi][ni] = __builtin_amdgcn_mfma_f32_16x16x32_bf16(
                    af[mi], bfr[ni], acc[mi][ni], 0, 0, 0);
    }

    // C/D layout: col = lane&15, row = (lane>>4)*4 + reg
    const int rb = m0 + wm + (lane >> 4) * 4;
    const int cb = n0 + wn + lm;
#pragma unroll
    for (int ni = 0; ni < 4; ni++) {
        const int col = cb + ni * 16;
        const float bv = bias[col];
#pragma unroll
        for (int mi = 0; mi < 4; mi++) {
#pragma unroll
            for (int r = 0; r < 4; r++) {
                const int row = rb + mi * 16 + r;
                float v = acc[mi][ni][r] + bv;
                if (EPI == 1) v = 0.5f * v * (1.f + erff(v * 0.70710678118654752f));
                if (EPI == 2) v += res[(size_t)row * N + col];
                Cc[(size_t)row * N + col] = (TO)v;
            }
        }
    }
}

// ---------------- Windowed attention: one block per (head, window) ----------------
// qkv/out pointers are CHUNK-LOCAL (a whole number of images each).
__global__ __launch_bounds__(256) void attn_k(const bf16* __restrict__ qkv,
    const float* __restrict__ rpb, bf16* __restrict__ out)
{
    const int hd = blockIdx.x;          // 0..11
    const int w  = blockIdx.y;          // 0..64*imgs-1
    const int bb = w >> 6, win = w & 63, wy = win >> 3, wx = win & 7;
    __shared__ int   toks[49];
    __shared__ float biasS[169];
    __shared__ __align__(16) float ks[49][36];
    __shared__ __align__(16) float vs[49][36];
    __shared__ float S[49][50];
    const int tid = threadIdx.x;
    if (tid < 49)
        toks[tid] = bb * 3136 + (wy * 7 + tid / 7) * 56 + wx * 7 + tid % 7;
    if (tid < 169) biasS[tid] = rpb[tid * 12 + hd];
    __syncthreads();
    // stage K,V (fp32) into LDS, 16B global loads
    for (int t = tid; t < 49 * 4; t += 256) {
        const int r = t >> 2, dc = (t & 3) * 8;
        const bf16* p = qkv + (size_t)toks[r] * 1152 + hd * 32 + dc;
        const bf16x8 kv = *(const bf16x8*)(p + 384);
        const bf16x8 vv = *(const bf16x8*)(p + 768);
#pragma unroll
        for (int e = 0; e < 8; e++) { ks[r][dc + e] = (float)kv[e]; vs[r][dc + e] = (float)vv[e]; }
    }
    __syncthreads();
    const int i = tid >> 2, q4 = tid & 3;   // 4 threads cooperate per query row
    if (i < 49) {
        float qr[32];
        const bf16* qp = qkv + (size_t)toks[i] * 1152 + hd * 32;
#pragma unroll
        for (int c = 0; c < 4; c++) {
            const bf16x8 qv = *(const bf16x8*)(qp + c * 8);
#pragma unroll
            for (int e = 0; e < 8; e++) qr[c * 8 + e] = (float)qv[e] * 0.1767766952966369f;
        }
        const int iy = i / 7, ix = i % 7;
        for (int j = q4; j < 49; j += 4) {
            float dot = 0.f;
#pragma unroll
            for (int dc = 0; dc < 8; dc++) {
                const float4 kk = *(const float4*)&ks[j][dc * 4];
                dot += qr[dc*4]*kk.x + qr[dc*4+1]*kk.y + qr[dc*4+2]*kk.z + qr[dc*4+3]*kk.w;
            }
            S[i][j] = dot + biasS[(iy - j / 7 + 6) * 13 + (ix - j % 7 + 6)];
        }
    }
    __syncthreads();
    if (tid < 49) {
        float mx = -1e30f;
        for (int j = 0; j < 49; j++) mx = fmaxf(mx, S[tid][j]);
        float sum = 0.f;
        for (int j = 0; j < 49; j++) { const float e = __expf(S[tid][j] - mx); S[tid][j] = e; sum += e; }
        const float inv = 1.f / sum;
        for (int j = 0; j < 49; j++) S[tid][j] *= inv;
    }
    __syncthreads();
    if (i < 49) {
        const int dc = q4 * 8;
        float acc[8] = {};
        for (int j = 0; j < 49; j++) {
            const float p = S[i][j];
            const float4 v0 = *(const float4*)&vs[j][dc];
            const float4 v1 = *(const float4*)&vs[j][dc + 4];
            acc[0] += p * v0.x; acc[1] += p * v0.y; acc[2] += p * v0.z; acc[3] += p * v0.w;
            acc[4] += p * v1.x; acc[5] += p * v1.y; acc[6] += p * v1.z; acc[7] += p * v1.w;
        }
        bf16x8 pk;
#pragma unroll
        for (int e = 0; e < 8; e++) pk[e] = (bf16)acc[e];
        *(bf16x8*)(out + (size_t)toks[i] * CDIM + hd * 32 + dc) = pk;
    }
}

extern "C" void kernel_launch(void* const* d_in, const int* in_sizes, int n_in,
                              void* d_out, int out_size, void* d_ws, size_t ws_size,
                              hipStream_t stream) {
    // All float tensors are fp32 per the reference; OUTPUT IS FP32 TOO.
    const float* x      = (const float*)d_in[0];
    const float* n1g    = (const float*)d_in[1];
    const float* n1b    = (const float*)d_in[2];
    const float* qkv_w  = (const float*)d_in[3];
    const float* qkv_b  = (const float*)d_in[4];
    const float* rpb    = (const float*)d_in[5];
    const float* proj_w = (const float*)d_in[6];
    const float* proj_b = (const float*)d_in[7];
    const float* n2g    = (const float*)d_in[8];
    const float* n2b    = (const float*)d_in[9];
    const float* fc1_w  = (const float*)d_in[10];
    const float* fc1_b  = (const float*)d_in[11];
    const float* fc2_w  = (const float*)d_in[12];
    const float* fc2_b  = (const float*)d_in[13];
    float* out = (float*)d_out;

    // Workspace layout:
    //   [0, 3538944):            bf16 weights (qkv 442368 | proj 147456 | fc1 589824 | fc2 589824)
    //   [3538944, +rowsC*768):   bufH  (LN out / attn-out chunk, bf16)
    //   [.., +rowsC*3072):       bufB  (qkv chunk 2304 B/row or fc1-out chunk 3072 B/row)
    // x1 (post-attention residual stream, fp32) lives in d_out.
    const size_t wBytes = 3538944;
    int nc = 16;
    for (int c : {1, 2, 4, 8}) {
        if (wBytes + ((size_t)NTOK / c) * 3840 <= ws_size) { nc = c; break; }
    }
    const int rowsC = NTOK / nc;
    const int imgsC = 32 / nc;

    char* ws = (char*)d_ws;
    bf16* wqkv  = (bf16*)ws;
    bf16* wproj = wqkv + 442368;
    bf16* wfc1  = wproj + 147456;
    bf16* wfc2  = wfc1 + 589824;
    bf16* bufH  = (bf16*)(ws + wBytes);
    bf16* bufB  = bufH + (size_t)rowsC * CDIM;
    float* x1   = out;                  // fp32 residual stream in d_out

    // 0) weights fp32 -> bf16
    cvt_k<<<442368 / 1024, 256, 0, stream>>>(qkv_w, wqkv, 442368);
    cvt_k<<<147456 / 1024, 256, 0, stream>>>(proj_w, wproj, 147456);
    cvt_k<<<589824 / 1024, 256, 0, stream>>>(fc1_w, wfc1, 589824);
    cvt_k<<<589824 / 1024, 256, 0, stream>>>(fc2_w, wfc2, 589824);

    // 1) attention path, chunked over images
    for (int c = 0; c < nc; c++) {
        const size_t ro = (size_t)c * rowsC;
        ln32_k<<<rowsC / 4, 256, 0, stream>>>(x + ro * CDIM, n1g, n1b, bufH);
        gemm_bt<0, bf16><<<dim3(1152 / 128, rowsC / 128), 256, 0, stream>>>(
            bufH, wqkv, qkv_b, nullptr, bufB, 1152, 384);
        attn_k<<<dim3(12, 64 * imgsC), 256, 0, stream>>>(bufB, rpb, bufH);
        // x1 = x + attn_out @ proj_w^T + proj_b   (fp32, into d_out)
        gemm_bt<2, float><<<dim3(384 / 128, rowsC / 128), 256, 0, stream>>>(
            bufH, wproj, proj_b, x + ro * CDIM, x1 + ro * CDIM, 384, 384);
    }
    // 2) MLP path, chunked
    for (int c = 0; c < nc; c++) {
        const size_t ro = (size_t)c * rowsC;
        ln32_k<<<rowsC / 4, 256, 0, stream>>>(x1 + ro * CDIM, n2g, n2b, bufH);
        gemm_bt<1, bf16><<<dim3(1536 / 128, rowsC / 128), 256, 0, stream>>>(
            bufH, wfc1, fc1_b, nullptr, bufB, 1536, 384);
        // out = x1 + gelu(h2@fc1^T+b1)@fc2^T + b2  (fp32; res==dst, read-before-write)
        gemm_bt<2, float><<<dim3(384 / 128, rowsC / 128), 256, 0, stream>>>(
            bufB, wfc2, fc2_b, x1 + ro * CDIM, out + ro * CDIM, 384, 1536);
    }
}